// Round 17
// baseline (206.570 us; speedup 1.0000x reference)
//
#include <hip/hip_runtime.h>
#include <hip/hip_bf16.h>
#include <math.h>

#define NN     50000
#define FIN    128
#define F1     64      // H1*C1 = layer-1 output features
#define NH1    8
#define F2     64      // layer-2 output features

#define BSH    256                         // nodes per dst bucket (CSR build)
#define NB     ((NN + BSH - 1) / BSH)      // 196 buckets
#define BCAP   9472                        // per-bucket edge cap (mean 8448, +11 sigma)
#define PREB   13                          // swizzle blocks in k_front
#define MG1B   ((NN + 255) / 256)          // 196 mgemm1 super-blocks in k_mid

typedef __bf16 bf16x8 __attribute__((ext_vector_type(8)));
typedef float  f32x4  __attribute__((ext_vector_type(4)));

// ---------------- runtime dtype helpers ----------------
// flags[0] = 1 if float tensors are fp32 (else bf16)
// flags[1] = 1 if edge_index is int64 (else int32)

__device__ __forceinline__ float loadF(const void* p, long long i, int fp32) {
    if (fp32) return ((const float*)p)[i];
    return __bfloat162float(((const __hip_bfloat16*)p)[i]);
}
__device__ __forceinline__ int loadI_nt(const void* p, long long i, int i64) {
    if (i64) return (int)__builtin_nontemporal_load(&((const long long*)p)[i]);
    return __builtin_nontemporal_load(&((const int*)p)[i]);
}
__device__ __forceinline__ unsigned short f2bfu(float f) {   // RNE f32->bf16 bits
    unsigned u = __float_as_uint(f);
    return (unsigned short)((u + 0x7FFFu + ((u >> 16) & 1u)) >> 16);
}
__device__ __forceinline__ float b2f(unsigned short u) {
    return __uint_as_float(((unsigned)u) << 16);
}

// ---------------- k_front: [sniff + W-swizzle] | [edge binning] (R15) ----------------

__global__ __launch_bounds__(1024) void k_front(
    const void* __restrict__ x, const void* __restrict__ ei, int E, int Etot,
    int* __restrict__ flags,
    const void* __restrict__ W1, const void* __restrict__ W2,
    unsigned short* __restrict__ W1p, unsigned short* __restrict__ W2p,
    int* __restrict__ bcnt, unsigned* __restrict__ binned) {
    __shared__ int s_a, s_b;
    __shared__ int hist[NB], gbase[NB];
    int tid = threadIdx.x;
    if (blockIdx.x < PREB) {
        if (tid == 0) { s_a = 0; s_b = 0; }
        __syncthreads();
        const unsigned short* u = (const unsigned short*)x;
        int cnt = 0;
        for (int i = tid; i < 8192; i += 1024) {
            unsigned short v = u[i];
            if ((v & 0x7F80) == 0x7F80) cnt++;     // bf16 Inf/NaN pattern
        }
        if (cnt) atomicAdd(&s_a, cnt);
        const unsigned* e32 = (const unsigned*)ei;
        int nz = 0;
        for (int i = tid; i < 2048; i += 1024) {
            if (e32[2 * i + 1] != 0u) nz++;        // high words if int64
        }
        if (nz) atomicAdd(&s_b, nz);
        __syncthreads();
        int fp32 = (s_a > 2) ? 1 : 0;
        if (tid == 0 && blockIdx.x == 0) {
            flags[0] = fp32;
            flags[1] = (s_b == 0) ? 1 : 0;
        }
        int gt = blockIdx.x * 1024 + tid, gs = PREB * 1024;
        for (int i = gt; i < (FIN / 32) * 4 * 512; i += gs) {   // 8192
            int j = i & 7, l = (i >> 3) & 63, f = i >> 9;
            int kb = f >> 2, nt = f & 3;
            int k = kb * 32 + (l >> 4) * 8 + j, n = nt * 16 + (l & 15);
            W1p[i] = f2bfu(loadF(W1, k * 64 + n, fp32));
        }
        for (int i = gt; i < (F1 / 32) * 4 * 512; i += gs) {    // 4096
            int j = i & 7, l = (i >> 3) & 63, f = i >> 9;
            int kb = f >> 2, nt = f & 3;
            int k = kb * 32 + (l >> 4) * 8 + j, n = nt * 16 + (l & 15);
            W2p[i] = f2bfu(loadF(W2, k * 64 + n, fp32));
        }
    } else {
        // ---- bin role (own int-width sniff) ----
        if (tid == 0) s_b = 0;
        for (int i = tid; i < NB; i += 1024) hist[i] = 0;
        __syncthreads();
        const unsigned* e32 = (const unsigned*)ei;
        int nz = 0;
        for (int i = tid; i < 2048; i += 1024) {
            if (e32[2 * i + 1] != 0u) nz++;
        }
        if (nz) atomicAdd(&s_b, nz);
        __syncthreads();
        int i64 = (s_b == 0) ? 1 : 0;
        long long base = (long long)(blockIdx.x - PREB) * 8192;
        unsigned pk[8]; short bb[8];
        #pragma unroll
        for (int u = 0; u < 8; ++u) {
            long long j = base + u * 1024 + tid;
            int s = -1, d = -1;
            if (j < Etot) {
                if (j < E) { s = loadI_nt(ei, j, i64); d = loadI_nt(ei, (long long)E + j, i64); }
                else       { s = d = (int)(j - E); }
            }
            if ((unsigned)s < NN && (unsigned)d < NN) {
                bb[u] = (short)(d >> 8);
                pk[u] = ((unsigned)s << 8) | (unsigned)(d & 255);
                atomicAdd(&hist[bb[u]], 1);
            } else bb[u] = -1;
        }
        __syncthreads();
        for (int i = tid; i < NB; i += 1024) {
            int h = hist[i];
            gbase[i] = h ? atomicAdd(&bcnt[i], h) : 0;
            hist[i] = 0;                             // reuse as local cursor
        }
        __syncthreads();
        #pragma unroll
        for (int u = 0; u < 8; ++u) {
            if (bb[u] >= 0) {
                int pos = gbase[bb[u]] + atomicAdd(&hist[bb[u]], 1);
                if (pos < BCAP) binned[(size_t)bb[u] * BCAP + pos] = pk[u];
            }
        }
    }
}

// ---------------- k_mid: [CSR counting sort] | [layer-1 MFMA GEMM] ----------------
// R17: fixed per-bucket perm bases (bk*BCAP) delete the redundant 196-entry
// phase-0 scan; per-dst segments published as dstart/dend pairs (perm
// ordering across buckets no longer globally contiguous — agg doesn't care).

__global__ __launch_bounds__(1024) void k_mid(
    const int* __restrict__ bcnt, const unsigned* __restrict__ binned,
    int* __restrict__ dstart, int* __restrict__ dend, int* __restrict__ perm,
    const void* __restrict__ x, const unsigned short* __restrict__ W1p,
    const void* __restrict__ attS, const void* __restrict__ attD,
    __hip_bfloat16* __restrict__ h1, float* __restrict__ a1s,
    float* __restrict__ a1d, const int* __restrict__ flags) {
    __shared__ __align__(16) char smem[33280];     // max(csr 3KB, mgemm 33KB)
    int tid = threadIdx.x;
    if (blockIdx.x < NB) {
        int* hist = (int*)smem;
        int* cur  = (int*)(smem + 1024);
        int* sd   = (int*)(smem + 2048);
        int bk = blockIdx.x;
        int n0 = bk * BSH;
        int gb = bk * BCAP;                        // fixed bucket base
        int cnt = bcnt[bk]; if (cnt > BCAP) cnt = BCAP;
        const unsigned* bp = binned + (size_t)bk * BCAP;
        if (tid < 256) hist[tid] = 0;
        __syncthreads();
        for (int i = tid; i < cnt; i += 1024)
            atomicAdd(&hist[bp[i] & 255], 1);
        __syncthreads();
        int myh = (tid < 256) ? hist[tid] : 0;
        if (tid < 256) sd[tid] = myh;
        __syncthreads();
        for (int off = 1; off < BSH; off <<= 1) {
            int t = 0;
            if (tid < 256 && tid >= off) t = sd[tid - off];
            __syncthreads();
            if (tid < 256) sd[tid] += t;
            __syncthreads();
        }
        if (tid < 256) {
            int excl = sd[tid] - myh;
            cur[tid] = gb + excl;
            if (n0 + tid < NN) {
                dstart[n0 + tid] = gb + excl;
                dend[n0 + tid]   = gb + excl + myh;
            }
        }
        __syncthreads();
        for (int i = tid; i < cnt; i += 1024) {
            unsigned pk = bp[i];
            int pos = atomicAdd(&cur[pk & 255], 1);
            perm[pos] = (int)(pk >> 8);
        }
    } else {
        // ---- mgemm1 role: 4 sub-tiles of 64 nodes ----
        int fp32 = flags[0];
        unsigned short* hl = (unsigned short*)smem;          // 4 x 4096 ushort
        float* attSl = (float*)(smem + 32768);
        float* attDl = (float*)(smem + 32768 + 256);
        if (tid < 64) { attSl[tid] = loadF(attS, tid, fp32); attDl[tid] = loadF(attD, tid, fp32); }
        int sub = tid >> 8, t = tid & 255;
        int w = t >> 6, l = t & 63;
        int quad = l >> 4, lm = l & 15;
        int n0 = (blockIdx.x - NB) * 256 + sub * 64;
        unsigned short* hls = hl + sub * 4096;

        bf16x8 bfr[16];
        #pragma unroll
        for (int f = 0; f < 16; ++f)
            bfr[f] = *(const bf16x8*)(W1p + f * 512 + l * 8);

        int nodeA = n0 + w * 16 + lm;
        long long rowA = (nodeA < NN) ? nodeA : 0;     // clamp; garbage unused
        f32x4 acc[4];
        #pragma unroll
        for (int nt = 0; nt < 4; ++nt) acc[nt] = (f32x4){0.f, 0.f, 0.f, 0.f};

        #pragma unroll
        for (int kb = 0; kb < 4; ++kb) {
            bf16x8 af;
            if (!fp32) {
                af = *(const bf16x8*)((const unsigned short*)x + rowA * FIN + kb * 32 + quad * 8);
            } else {
                const float* xf = (const float*)x + rowA * FIN + kb * 32 + quad * 8;
                union { unsigned short s[8]; bf16x8 v; } tmp;
                #pragma unroll
                for (int j = 0; j < 8; ++j) tmp.s[j] = f2bfu(xf[j]);
                af = tmp.v;
            }
            #pragma unroll
            for (int nt = 0; nt < 4; ++nt)
                acc[nt] = __builtin_amdgcn_mfma_f32_16x16x32_bf16(af, bfr[kb * 4 + nt], acc[nt], 0, 0, 0);
        }

        #pragma unroll
        for (int nt = 0; nt < 4; ++nt) {
            #pragma unroll
            for (int r = 0; r < 4; ++r) {
                int nl = w * 16 + quad * 4 + r;
                int node = n0 + nl;
                int c = nt * 16 + lm;
                unsigned short hb = f2bfu(acc[nt][r]);
                hls[nl * 64 + c] = hb;
                if (node < NN) ((unsigned short*)h1)[(size_t)node * 64 + c] = hb;
            }
        }
        __syncthreads();
        // a1s/a1d per (node, head): 64 nodes x 8 heads = 512 pairs per sub
        #pragma unroll
        for (int pp = 0; pp < 2; ++pp) {
            int p = t + pp * 256;
            int nl = p >> 3, g = p & 7;
            int node = n0 + nl;
            float ss = 0.f, dd = 0.f;
            #pragma unroll
            for (int j = 0; j < 8; ++j) {
                float hv = b2f(hls[nl * 64 + g * 8 + j]);
                ss += hv * attSl[g * 8 + j];
                dd += hv * attDl[g * 8 + j];
            }
            if (node < NN) {
                a1s[(size_t)node * NH1 + g] = ss;
                a1d[(size_t)node * NH1 + g] = dd;
            }
        }
    }
}

// ---------------- Fused layer-1 agg + layer-2 GEMM + scalar projection ----------------
// R17: block = 1024 thr = 16 waves, ONE dst per wave (restores R12's 50000-wave
// latency profile that measured 46.6us; R13's 4-dst-serial was 55-57). Phase 2
// (MFMA + epilogue) runs on waves 0-3 only; waves 4-15 just hit the barriers.

#define HLP 72

__global__ __launch_bounds__(1024) void k_agg1f(
    const int* __restrict__ dstart, const int* __restrict__ dend,
    const int* __restrict__ perm,
    const __hip_bfloat16* __restrict__ h1, const float* __restrict__ a1s,
    const float* __restrict__ a1d, const void* __restrict__ b1,
    const unsigned short* __restrict__ W2p,
    const void* __restrict__ attS2, const void* __restrict__ attD2,
    const void* __restrict__ linW,
    float2* __restrict__ g2s, float* __restrict__ a2d,
    int n, const int* __restrict__ flags) {
    int fp32 = flags[0];
    __shared__ unsigned short hl[16 * HLP];   // 2.25 KB helu tile (bf16 bits)
    __shared__ float attSl[64], attDl[64];
    __shared__ float sp[16 * 4], dp[16 * 4], gp[16 * 4];
    int tid = threadIdx.x;
    if (tid < 64) { attSl[tid] = loadF(attS2, tid, fp32); attDl[tid] = loadF(attD2, tid, fp32); }
    int wave = tid >> 6, c = tid & 63;
    int n0 = blockIdx.x * 16;
    int u = c & 7, h = c >> 3, cb = c & 56;
    const unsigned short* hu = (const unsigned short*)h1;

    // ---- phase 1: each wave aggregates ONE dst (R12 loop, verbatim) ----
    int d = n0 + wave;
    if (d < n) {
        int start = dstart[d], end = dend[d];
        float adl = a1d[(size_t)d * NH1 + h];
        float acc = 0.f, denp = 0.f;
        for (int i = start; i < end; i += 8) {
            int j = i + u;
            int jc = (j < end) ? j : (end - 1);
            int sj = perm[jc];
            float e = a1s[(size_t)sj * NH1 + h] + adl;
            e = fmaxf(e, 0.2f * e);                      // leaky_relu(0.2)
            float p = (j < end) ? __expf(e) : 0.f;
            denp += p;
            #pragma unroll
            for (int k = 0; k < 8; ++k) {
                int su = __builtin_amdgcn_readlane(sj, k);   // wave-uniform src
                float pk = __shfl(p, cb + k, 64);            // p(edge k, my head)
                acc = fmaf(pk, b2f(hu[(size_t)su * 64 + c]), acc);
            }
        }
        denp += __shfl_xor(denp, 1, 64);
        denp += __shfl_xor(denp, 2, 64);
        denp += __shfl_xor(denp, 4, 64);                 // den for head c>>3
        float v = acc / (denp + 1e-16f) + loadF(b1, c, fp32);
        v = (v > 0.f) ? v : expm1f(v);                   // ELU
        hl[wave * HLP + c] = f2bfu(v);
    }
    __syncthreads();

    // ---- phase 2 (waves 0-3): h2 tile = hl @ W2; g2/a2s/a2d epilogue ----
    if (tid < 256) {
        int w = tid >> 6;
        int quad = c >> 4, lm = c & 15;
        bf16x8 bf0 = *(const bf16x8*)(W2p + (0 * 4 + w) * 512 + c * 8);
        bf16x8 bf1 = *(const bf16x8*)(W2p + (1 * 4 + w) * 512 + c * 8);
        bf16x8 af0 = *(const bf16x8*)(hl + lm * HLP + 0 * 32 + quad * 8);
        bf16x8 af1 = *(const bf16x8*)(hl + lm * HLP + 1 * 32 + quad * 8);
        f32x4 acc2 = (f32x4){0.f, 0.f, 0.f, 0.f};
        acc2 = __builtin_amdgcn_mfma_f32_16x16x32_bf16(af0, bf0, acc2, 0, 0, 0);
        acc2 = __builtin_amdgcn_mfma_f32_16x16x32_bf16(af1, bf1, acc2, 0, 0, 0);

        int cg = w * 16 + lm;                                // global output col
        float aSc = attSl[cg], aDc = attDl[cg];
        float lWc = loadF(linW, cg, fp32);
        #pragma unroll
        for (int r = 0; r < 4; ++r) {
            int nl = quad * 4 + r;
            unsigned short hb = f2bfu(acc2[r]);              // same rounding as before
            float hv = b2f(hb);
            float pvs = hv * aSc, pvd = hv * aDc, pvg = hv * lWc;
            pvs += __shfl_xor(pvs, 1, 64); pvd += __shfl_xor(pvd, 1, 64); pvg += __shfl_xor(pvg, 1, 64);
            pvs += __shfl_xor(pvs, 2, 64); pvd += __shfl_xor(pvd, 2, 64); pvg += __shfl_xor(pvg, 2, 64);
            pvs += __shfl_xor(pvs, 4, 64); pvd += __shfl_xor(pvd, 4, 64); pvg += __shfl_xor(pvg, 4, 64);
            pvs += __shfl_xor(pvs, 8, 64); pvd += __shfl_xor(pvd, 8, 64); pvg += __shfl_xor(pvg, 8, 64);
            if (lm == 0) { sp[nl * 4 + w] = pvs; dp[nl * 4 + w] = pvd; gp[nl * 4 + w] = pvg; }
        }
    }
    __syncthreads();
    if (tid < 16) {
        int node = n0 + tid;
        if (node < n) {
            float ss = sp[tid * 4 + 0] + sp[tid * 4 + 1] + sp[tid * 4 + 2] + sp[tid * 4 + 3];
            float dd = dp[tid * 4 + 0] + dp[tid * 4 + 1] + dp[tid * 4 + 2] + dp[tid * 4 + 3];
            float gg = gp[tid * 4 + 0] + gp[tid * 4 + 1] + gp[tid * 4 + 2] + gp[tid * 4 + 3];
            g2s[node] = make_float2(ss, gg);
            a2d[node] = dd;
        }
    }
}

// ---------------- Layer 2 aggregation, scalar form (R16) ----------------

__global__ __launch_bounds__(256) void k_agg2(
    const int* __restrict__ dstart, const int* __restrict__ dend,
    const int* __restrict__ perm,
    const float2* __restrict__ g2s, const float* __restrict__ a2d,
    const void* __restrict__ b2, const void* __restrict__ linW,
    const void* __restrict__ linb,
    void* __restrict__ out, int n, const int* __restrict__ flags) {
    int fp32 = flags[0];
    int w = threadIdx.x >> 6, c = threadIdx.x & 63;
    int d = blockIdx.x * 4 + w;
    if (d >= n) return;
    int start = dstart[d], end = dend[d];
    float ad = a2d[d];
    float acc = 0.f, den = 0.f;
    for (int i = start + c; i < end; i += 64) {
        int s = perm[i];
        float2 ag = g2s[s];
        float e = ag.x + ad;
        e = fmaxf(e, 0.2f * e);                      // leaky_relu(0.2)
        float p = __expf(e);
        acc = fmaf(p, ag.y, acc);
        den += p;
    }
    float cst = loadF(b2, c, fp32) * loadF(linW, c, fp32);   // b2·linW partial
    #pragma unroll
    for (int off = 1; off < 64; off <<= 1) {
        acc += __shfl_xor(acc, off, 64);
        den += __shfl_xor(den, off, 64);
        cst += __shfl_xor(cst, off, 64);
    }
    if (c == 0) {
        float r = acc / (den + 1e-16f) + cst + loadF(linb, 0, fp32);
        if (fp32) ((float*)out)[d] = r;
        else      ((__hip_bfloat16*)out)[d] = __float2bfloat16(r);
    }
}

// ---------------- host launcher ----------------

static inline char* carve(char*& p, size_t bytes) {
    char* r = p;
    p += (bytes + 255) & ~size_t(255);
    return r;
}

extern "C" void kernel_launch(void* const* d_in, const int* in_sizes, int n_in,
                              void* d_out, int out_size, void* d_ws, size_t ws_size,
                              hipStream_t stream) {
    const void* x     = d_in[0];
    const void* ei    = d_in[1];
    const void* W1    = d_in[2];
    const void* attS1 = d_in[3];
    const void* attD1 = d_in[4];
    const void* b1    = d_in[5];
    const void* W2    = d_in[6];
    const void* attS2 = d_in[7];
    const void* attD2 = d_in[8];
    const void* b2    = d_in[9];
    const void* linW  = d_in[10];
    const void* linb  = d_in[11];

    int E    = in_sizes[1] / 2;
    int Etot = E + NN;

    // workspace layout (~26 MB)
    char* p = (char*)d_ws;
    int*   flags = (int*)carve(p, 256);
    int*   bcnt  = (int*)carve(p, (size_t)NB * 4);
    unsigned short* W1p = (unsigned short*)carve(p, 8192 * 2);
    unsigned short* W2p = (unsigned short*)carve(p, 4096 * 2);
    int*   dstart = (int*)carve(p, (size_t)NN * 4);            // 200 KB
    int*   dend   = (int*)carve(p, (size_t)NN * 4);            // 200 KB
    int*   perm   = (int*)carve(p, (size_t)NB * BCAP * 4);     // 7.43 MB (fixed bases)
    // binned has its own region (k_mid overlaps csr reads with mgemm writes)
    unsigned* binned = (unsigned*)carve(p, (size_t)NB * BCAP * 4);  // 7.43 MB
    float*    a1s    = (float*)carve(p, (size_t)NN * NH1 * 4);      // 1.6 MB
    float*    a1d    = (float*)carve(p, (size_t)NN * NH1 * 4);      // 1.6 MB
    __hip_bfloat16* h1 = (__hip_bfloat16*)carve(p, (size_t)NN * F1 * 2);  // 6.4 MB
    float2* g2s = (float2*)carve(p, (size_t)NN * 8);           // 400 KB (a2s, g2)
    float*  a2d = (float*)carve(p, (size_t)NN * 4);            // 200 KB

    hipMemsetAsync(bcnt, 0, (size_t)NB * 4, stream);

    int nbin = (Etot + 8191) / 8192;
    k_front<<<PREB + nbin, 1024, 0, stream>>>(x, ei, E, Etot, flags,
                                              W1, W2, W1p, W2p, bcnt, binned);
    k_mid<<<NB + MG1B, 1024, 0, stream>>>(bcnt, binned, dstart, dend, perm,
                                          x, W1p, attS1, attD1, h1, a1s, a1d, flags);
    k_agg1f<<<(NN + 15) / 16, 1024, 0, stream>>>(dstart, dend, perm, h1, a1s, a1d, b1,
                                                 W2p, attS2, attD2, linW, g2s, a2d, NN, flags);
    k_agg2<<<(NN + 3) / 4, 256, 0, stream>>>(dstart, dend, perm, g2s, a2d, b2, linW, linb, d_out, NN, flags);
}